// Round 1
// baseline (321.956 us; speedup 1.0000x reference)
//
#include <hip/hip_runtime.h>
#include <stdint.h>
#include <stddef.h>

// Multi-head attention: x@w_qkv+b -> split heads -> softmax(QK^T/sqrt(D))V -> @w_proj+b
// B=8 N=1024 C=1024 H=16 D=64. bf16 MFMA pipeline, fp32 accum, fp32 softmax.

#define DEVI __device__ __forceinline__

typedef float f32x4 __attribute__((ext_vector_type(4)));
typedef __bf16 bf16x8 __attribute__((ext_vector_type(8)));
typedef unsigned short u16x8 __attribute__((ext_vector_type(8)));
typedef unsigned short u16x4 __attribute__((ext_vector_type(4)));

static constexpr int BB = 8, NN = 1024, CC = 1024, HH = 16, DD = 64;
static constexpr int M1 = BB * NN;   // 8192 rows

DEVI unsigned short f2bf(float f) {
  uint32_t u = __builtin_bit_cast(uint32_t, f);
  u += 0x7FFFu + ((u >> 16) & 1u);   // round-to-nearest-even
  return (unsigned short)(u >> 16);
}

DEVI void gll16(const unsigned short* g, unsigned short* lds) {
  __builtin_amdgcn_global_load_lds(
      (const __attribute__((address_space(1))) void*)g,
      (__attribute__((address_space(3))) void*)lds, 16, 0, 0);
}

DEVI bf16x8 lds_frag(const unsigned short* p) {
  return __builtin_bit_cast(bf16x8, *(const u16x8*)p);
}

// ---------------- convert x fp32 -> bf16 ----------------
__global__ void k_cvt(const float* __restrict__ in, unsigned short* __restrict__ out, int n4) {
  int i = blockIdx.x * blockDim.x + threadIdx.x;
  if (i < n4) {
    float4 v = reinterpret_cast<const float4*>(in)[i];
    u16x4 o = { f2bf(v.x), f2bf(v.y), f2bf(v.z), f2bf(v.w) };
    reinterpret_cast<u16x4*>(out)[i] = o;
  }
}

// ---------------- transpose + convert weights: in[R][C] fp32 -> out[C][R] bf16 ----------------
__global__ void k_tr_cvt(const float* __restrict__ in, unsigned short* __restrict__ out,
                         int R, int Cc) {
  __shared__ float tile[32][33];
  int c0 = blockIdx.x * 32, r0 = blockIdx.y * 32;
  int tx = threadIdx.x, ty = threadIdx.y;   // blockDim (32,8)
#pragma unroll
  for (int j = 0; j < 32; j += 8)
    tile[ty + j][tx] = in[(size_t)(r0 + ty + j) * Cc + c0 + tx];
  __syncthreads();
#pragma unroll
  for (int j = 0; j < 32; j += 8)
    out[(size_t)(c0 + ty + j) * R + r0 + tx] = f2bf(tile[tx][ty + j]);
}

// ---------------- GEMM: C[M x NCOLS] = A[M x 1024] * Bt[NCOLS x 1024]^T ----------------
// 128x128 tile, BK=32, 4 waves each 64x64 (4x4 frags of 16x16x32 bf16 MFMA).
// LDS double-buffered, staged via global_load_lds w/ pre-swizzled source.
// EPI==1: +bias, scatter to Q (pre-scaled 1/8), K [B,H,N,D], Vt [B,H,D,N] (bf16)
// EPI==2: +bias, fp32 store to Out[M x 1024]
template <int EPI, int NCOLS>
__global__ __launch_bounds__(256, 2)
void k_gemm(const unsigned short* __restrict__ A,
            const unsigned short* __restrict__ Bt,
            const float* __restrict__ bias,
            unsigned short* __restrict__ Qp,
            unsigned short* __restrict__ Kp,
            unsigned short* __restrict__ Vtp,
            float* __restrict__ Out) {
  constexpr int K = 1024, NK = K / 32;
  __shared__ unsigned short As[2][128 * 32];
  __shared__ unsigned short Bs[2][128 * 32];

  const int tid = threadIdx.x;
  const int w = tid >> 6, l = tid & 63;
  const int ln = l & 15, kg = l >> 4;
  const int wr = w >> 1, wc = w & 1;

  const int rt = blockIdx.x % (M1 / 128);
  const int ct = blockIdx.x / (M1 / 128);
  const int row0 = rt * 128, col0 = ct * 128;

  f32x4 acc[4][4] = {};

  const unsigned short* Ag = A + (size_t)row0 * K;
  const unsigned short* Bg = Bt + (size_t)col0 * K;

  auto stage = [&](int buf, int kt) {
    const unsigned short* ga = Ag + kt * 32;
    const unsigned short* gb = Bg + kt * 32;
#pragma unroll
    for (int j = 0; j < 2; j++) {
      int c = j * 256 + w * 64 + l;
      int r = c >> 2, s = c & 3;
      int ss = s ^ ((r >> 1) & 3);           // XOR swizzle (inverse applied on read)
      gll16(ga + (size_t)r * K + ss * 8, &As[buf][(j * 256 + w * 64) * 8]);
      gll16(gb + (size_t)r * K + ss * 8, &Bs[buf][(j * 256 + w * 64) * 8]);
    }
  };

  stage(0, 0);
  __syncthreads();

  int buf = 0;
  for (int kt = 0; kt < NK; kt++) {
    if (kt + 1 < NK) stage(buf ^ 1, kt + 1);

    bf16x8 af[4], bfr[4];
#pragma unroll
    for (int m = 0; m < 4; m++) {
      int r = wr * 64 + m * 16 + ln;
      int sl = kg ^ ((r >> 1) & 3);
      af[m] = lds_frag(&As[buf][r * 32 + sl * 8]);
    }
#pragma unroll
    for (int n = 0; n < 4; n++) {
      int r = wc * 64 + n * 16 + ln;
      int sl = kg ^ ((r >> 1) & 3);
      bfr[n] = lds_frag(&Bs[buf][r * 32 + sl * 8]);
    }
#pragma unroll
    for (int m = 0; m < 4; m++)
#pragma unroll
      for (int n = 0; n < 4; n++)
        acc[m][n] = __builtin_amdgcn_mfma_f32_16x16x32_bf16(af[m], bfr[n], acc[m][n], 0, 0, 0);

    __syncthreads();
    buf ^= 1;
  }

  // epilogue: C/D layout col = ln, row = kg*4 + reg (within 16x16)
#pragma unroll
  for (int n = 0; n < 4; n++) {
    int col = col0 + wc * 64 + n * 16 + ln;
    float bv = bias[col];
    if constexpr (EPI == 1) {
      int three = col >> 10, rem = col & 1023;
      int h = rem >> 6, d = rem & 63;
#pragma unroll
      for (int m = 0; m < 4; m++)
#pragma unroll
        for (int r = 0; r < 4; r++) {
          int row = row0 + wr * 64 + m * 16 + kg * 4 + r;
          int bb = row >> 10, nn = row & 1023;
          float v = acc[m][n][r] + bv;
          if (three == 0)
            Qp[((size_t)(bb * 16 + h) * 1024 + nn) * 64 + d] = f2bf(v * 0.125f);
          else if (three == 1)
            Kp[((size_t)(bb * 16 + h) * 1024 + nn) * 64 + d] = f2bf(v);
          else
            Vtp[((size_t)(bb * 16 + h) * 64 + d) * 1024 + nn] = f2bf(v);
        }
    } else {
#pragma unroll
      for (int m = 0; m < 4; m++)
#pragma unroll
        for (int r = 0; r < 4; r++) {
          int row = row0 + wr * 64 + m * 16 + kg * 4 + r;
          Out[(size_t)row * 1024 + col] = acc[m][n][r] + bv;
        }
    }
  }
}

// ---------------- flash attention ----------------
// grid (8 q-tiles, 128 bh). 4 waves x 32 q-rows, KVBLK=64, online softmax.
__global__ __launch_bounds__(256, 2)
void k_attn(const unsigned short* __restrict__ Qg, const unsigned short* __restrict__ Kg,
            const unsigned short* __restrict__ Vtg, unsigned short* __restrict__ AO) {
  __shared__ unsigned short Ks[2][64 * 64];
  __shared__ unsigned short Vs[2][64 * 64];
  __shared__ unsigned short Pl[4][32 * 72];   // stride 72 elems = 144B (16B-aligned rows)

  const int tid = threadIdx.x;
  const int w = tid >> 6, l = tid & 63;
  const int ln = l & 15, kg = l >> 4;

  const int qt = blockIdx.x;
  const int bh = blockIdx.y;
  const int qbase = qt * 128 + w * 32;

  // Q fragments in registers (Q was pre-scaled by 1/sqrt(D) at GEMM1 epilogue)
  bf16x8 qf[2][2];
#pragma unroll
  for (int m = 0; m < 2; m++)
#pragma unroll
    for (int kk = 0; kk < 2; kk++) {
      size_t off = ((size_t)bh * 1024 + qbase + m * 16 + ln) * 64 + kk * 32 + kg * 8;
      qf[m][kk] = __builtin_bit_cast(bf16x8, *(const u16x8*)(Qg + off));
    }

  f32x4 acc[2][4] = {};
  float mrun[2][4], lrun[2][4];
#pragma unroll
  for (int m = 0; m < 2; m++)
#pragma unroll
    for (int r = 0; r < 4; r++) { mrun[m][r] = -1e30f; lrun[m][r] = 0.f; }

  const unsigned short* Kbh = Kg + (size_t)bh * 1024 * 64;
  const unsigned short* Vbh = Vtg + (size_t)bh * 64 * 1024;

  auto stage = [&](int buf, int t) {
#pragma unroll
    for (int j = 0; j < 2; j++) {
      int c = j * 256 + w * 64 + l;
      int r = c >> 3, s = c & 7;
      int ss = s ^ (r & 7);
      gll16(Kbh + (size_t)(t * 64 + r) * 64 + ss * 8, &Ks[buf][(j * 256 + w * 64) * 8]);
      gll16(Vbh + (size_t)r * 1024 + t * 64 + ss * 8, &Vs[buf][(j * 256 + w * 64) * 8]);
    }
  };

  stage(0, 0);
  __syncthreads();

  int buf = 0;
  for (int t = 0; t < 16; t++) {
    if (t + 1 < 16) stage(buf ^ 1, t + 1);

    // S = Q K^T (scores, already scaled)
    f32x4 s[2][4] = {};
#pragma unroll
    for (int kk = 0; kk < 2; kk++) {
      bf16x8 kb[4];
#pragma unroll
      for (int n = 0; n < 4; n++) {
        int key = n * 16 + ln;
        int slot = (kk * 4 + kg) ^ (key & 7);
        kb[n] = lds_frag(&Ks[buf][key * 64 + slot * 8]);
      }
#pragma unroll
      for (int m = 0; m < 2; m++)
#pragma unroll
        for (int n = 0; n < 4; n++)
          s[m][n] = __builtin_amdgcn_mfma_f32_16x16x32_bf16(qf[m][kk], kb[n], s[m][n], 0, 0, 0);
    }

    // online softmax (rows owned per (m,reg); reduce across 16-lane group + 4 n-frags)
    float p[2][4][4];
#pragma unroll
    for (int m = 0; m < 2; m++)
#pragma unroll
      for (int r = 0; r < 4; r++) {
        float mx = fmaxf(fmaxf(s[m][0][r], s[m][1][r]), fmaxf(s[m][2][r], s[m][3][r]));
        mx = fmaxf(mx, __shfl_xor(mx, 1));
        mx = fmaxf(mx, __shfl_xor(mx, 2));
        mx = fmaxf(mx, __shfl_xor(mx, 4));
        mx = fmaxf(mx, __shfl_xor(mx, 8));
        float mnew = fmaxf(mrun[m][r], mx);
        float alpha = __expf(mrun[m][r] - mnew);
        mrun[m][r] = mnew;
        float rs = 0.f;
#pragma unroll
        for (int n = 0; n < 4; n++) {
          float pv = __expf(s[m][n][r] - mnew);
          p[m][n][r] = pv;
          rs += pv;
        }
        rs += __shfl_xor(rs, 1);
        rs += __shfl_xor(rs, 2);
        rs += __shfl_xor(rs, 4);
        rs += __shfl_xor(rs, 8);
        lrun[m][r] = lrun[m][r] * alpha + rs;
#pragma unroll
        for (int n = 0; n < 4; n++) acc[m][n][r] *= alpha;
      }

    // P -> LDS (per-wave private region; layout [q][key], padded stride 72)
#pragma unroll
    for (int m = 0; m < 2; m++)
#pragma unroll
      for (int n = 0; n < 4; n++)
#pragma unroll
        for (int r = 0; r < 4; r++)
          Pl[w][(m * 16 + kg * 4 + r) * 72 + n * 16 + ln] = f2bf(p[m][n][r]);

    // O += P V
#pragma unroll
    for (int kk = 0; kk < 2; kk++) {
      bf16x8 pa[2];
#pragma unroll
      for (int m = 0; m < 2; m++)
        pa[m] = lds_frag(&Pl[w][(m * 16 + ln) * 72 + kk * 32 + kg * 8]);
#pragma unroll
      for (int n = 0; n < 4; n++) {
        int d = n * 16 + ln;
        int slot = (kk * 4 + kg) ^ (d & 7);
        bf16x8 vb = lds_frag(&Vs[buf][d * 64 + slot * 8]);
#pragma unroll
        for (int m = 0; m < 2; m++)
          acc[m][n] = __builtin_amdgcn_mfma_f32_16x16x32_bf16(pa[m], vb, acc[m][n], 0, 0, 0);
      }
    }

    __syncthreads();
    buf ^= 1;
  }

  // normalize + store AO [B,N,H*D] bf16
  const int b = bh >> 4, h = bh & 15;
#pragma unroll
  for (int m = 0; m < 2; m++)
#pragma unroll
    for (int n = 0; n < 4; n++)
#pragma unroll
      for (int r = 0; r < 4; r++) {
        int row = qbase + m * 16 + kg * 4 + r;
        int col = h * 64 + n * 16 + ln;
        float v = acc[m][n][r] / lrun[m][r];
        AO[((size_t)(b * 1024 + row)) * 1024 + col] = f2bf(v);
      }
}

// ---------------- launch ----------------
extern "C" void kernel_launch(void* const* d_in, const int* in_sizes, int n_in,
                              void* d_out, int out_size, void* d_ws, size_t ws_size,
                              hipStream_t stream) {
  const float* x      = (const float*)d_in[0];
  const float* w_qkv  = (const float*)d_in[1];
  const float* b_qkv  = (const float*)d_in[2];
  const float* w_proj = (const float*)d_in[3];
  const float* b_proj = (const float*)d_in[4];
  float* out = (float*)d_out;

  // workspace layout (bytes)
  constexpr size_t SZ_XB   = (size_t)8192 * 1024 * 2;   // 16.78 MB
  constexpr size_t SZ_WQ   = (size_t)3072 * 1024 * 2;   //  6.29 MB
  constexpr size_t SZ_WP   = (size_t)1024 * 1024 * 2;   //  2.10 MB
  constexpr size_t SZ_QKV  = (size_t)8 * 16 * 1024 * 64 * 2; // 16.78 MB each
  char* ws = (char*)d_ws;
  unsigned short* xb    = (unsigned short*)(ws);
  unsigned short* wqkvT = (unsigned short*)(ws + SZ_XB);
  unsigned short* wprojT= (unsigned short*)(ws + SZ_XB + SZ_WQ);
  unsigned short* Qb    = (unsigned short*)(ws + SZ_XB + SZ_WQ + SZ_WP);
  unsigned short* Kb    = (unsigned short*)(ws + SZ_XB + SZ_WQ + SZ_WP + SZ_QKV);
  unsigned short* Vtb   = (unsigned short*)(ws + SZ_XB + SZ_WQ + SZ_WP + 2 * SZ_QKV);
  unsigned short* AOb   = (unsigned short*)(ws + SZ_XB + SZ_WQ + SZ_WP + 3 * SZ_QKV);
  size_t needed = SZ_XB + SZ_WQ + SZ_WP + 4 * SZ_QKV;   // ~92.3 MB
  if (ws_size < needed) return;

  // 1) convert x to bf16
  k_cvt<<<8192, 256, 0, stream>>>(x, xb, 8192 * 1024 / 4);
  // 2) transpose+convert weights to [N][K] bf16
  dim3 tb(32, 8);
  k_tr_cvt<<<dim3(96, 32), tb, 0, stream>>>(w_qkv, wqkvT, 1024, 3072);
  k_tr_cvt<<<dim3(32, 32), tb, 0, stream>>>(w_proj, wprojT, 1024, 1024);
  // 3) QKV GEMM -> Q(scaled), K, Vt
  k_gemm<1, 3072><<<64 * 24, 256, 0, stream>>>(xb, wqkvT, b_qkv, Qb, Kb, Vtb, nullptr);
  // 4) flash attention -> AO
  k_attn<<<dim3(8, 128), 256, 0, stream>>>(Qb, Kb, Vtb, AOb);
  // 5) projection GEMM -> out (fp32)
  k_gemm<2, 1024><<<64 * 8, 256, 0, stream>>>(AOb, wprojT, b_proj, nullptr, nullptr, nullptr, out);
}

// Round 2
// 307.923 us; speedup vs baseline: 1.0456x; 1.0456x over previous
//
#include <hip/hip_runtime.h>
#include <stdint.h>
#include <stddef.h>

// Multi-head attention: x@w_qkv+b -> heads -> softmax(QK^T/sqrt(D))V -> @w_proj+b
// B=8 N=1024 C=1024 H=16 D=64. bf16 MFMA, fp32 accum, fp32 softmax (log2 domain).

#define DEVI __device__ __forceinline__

typedef float f32x4 __attribute__((ext_vector_type(4)));
typedef __bf16 bf16x8 __attribute__((ext_vector_type(8)));
typedef unsigned short u16x8 __attribute__((ext_vector_type(8)));
typedef unsigned short u16x4 __attribute__((ext_vector_type(4)));

static constexpr int M1 = 8192;   // B*N rows

DEVI unsigned short f2bf(float f) {
  uint32_t u = __builtin_bit_cast(uint32_t, f);
  u += 0x7FFFu + ((u >> 16) & 1u);   // RNE
  return (unsigned short)(u >> 16);
}

DEVI float fexp2(float x) {        // 2^x via v_exp_f32 (CDNA: no trans-use hazard)
  float r;
  asm("v_exp_f32 %0, %1" : "=v"(r) : "v"(x));
  return r;
}

DEVI void gll16(const unsigned short* g, unsigned short* lds) {
  __builtin_amdgcn_global_load_lds(
      (const __attribute__((address_space(1))) void*)g,
      (__attribute__((address_space(3))) void*)lds, 16, 0, 0);
}

DEVI bf16x8 lds_frag(const unsigned short* p) {
  return __builtin_bit_cast(bf16x8, *(const u16x8*)p);
}

// ---------------- convert x fp32 -> bf16 ----------------
__global__ void k_cvt(const float* __restrict__ in, unsigned short* __restrict__ out, int n4) {
  int i = blockIdx.x * blockDim.x + threadIdx.x;
  if (i < n4) {
    float4 v = reinterpret_cast<const float4*>(in)[i];
    u16x4 o = { f2bf(v.x), f2bf(v.y), f2bf(v.z), f2bf(v.w) };
    reinterpret_cast<u16x4*>(out)[i] = o;
  }
}

// ---------------- transpose + convert weights: in[R][C] fp32 -> out[C][R] bf16 ----------------
__global__ void k_tr_cvt(const float* __restrict__ in, unsigned short* __restrict__ out,
                         int R, int Cc) {
  __shared__ float tile[32][33];
  int c0 = blockIdx.x * 32, r0 = blockIdx.y * 32;
  int tx = threadIdx.x, ty = threadIdx.y;   // blockDim (32,8)
#pragma unroll
  for (int j = 0; j < 32; j += 8)
    tile[ty + j][tx] = in[(size_t)(r0 + ty + j) * Cc + c0 + tx];
  __syncthreads();
#pragma unroll
  for (int j = 0; j < 32; j += 8)
    out[(size_t)(c0 + ty + j) * R + r0 + tx] = f2bf(tile[tx][ty + j]);
}

// ---------------- bf16 transpose V[bh][n][64] -> Vt[bh][64][n] ----------------
__global__ void k_tr_v(const unsigned short* __restrict__ in, unsigned short* __restrict__ out) {
  __shared__ unsigned short t[32][33];
  int d0 = blockIdx.x * 32, n0 = blockIdx.y * 32, bh = blockIdx.z;
  const unsigned short* ip = in + (size_t)bh * 1024 * 64;
  unsigned short* op = out + (size_t)bh * 64 * 1024;
  int tx = threadIdx.x, ty = threadIdx.y;   // blockDim (32,8)
#pragma unroll
  for (int j = 0; j < 32; j += 8)
    t[ty + j][tx] = ip[(size_t)(n0 + ty + j) * 64 + d0 + tx];
  __syncthreads();
#pragma unroll
  for (int j = 0; j < 32; j += 8)
    op[(size_t)(d0 + ty + j) * 1024 + n0 + tx] = t[tx][ty + j];
}

// ---------------- GEMM: C[M x NCOLS] = A[M x 1024] * Bt[NCOLS x 1024]^T ----------------
// 128x128 tile, BK=32, 4 waves each 64x64 (4x4 frags of 16x16x32 bf16 MFMA).
// EPI==1: +bias, scatter Q (pre-scaled log2e/8), K, V all [B,H,N,D] bf16 (coalesced)
// EPI==2: +bias, fp32 store to Out[M x 1024]
template <int EPI, int NCOLS>
__global__ __launch_bounds__(256, 2)
void k_gemm(const unsigned short* __restrict__ A,
            const unsigned short* __restrict__ Bt,
            const float* __restrict__ bias,
            unsigned short* __restrict__ Qp,
            unsigned short* __restrict__ Kp,
            unsigned short* __restrict__ Vp,
            float* __restrict__ Out) {
  constexpr int K = 1024, NK = K / 32;
  __shared__ unsigned short As[2][128 * 32];
  __shared__ unsigned short Bs[2][128 * 32];

  const int tid = threadIdx.x;
  const int w = tid >> 6, l = tid & 63;
  const int ln = l & 15, kg = l >> 4;
  const int wr = w >> 1, wc = w & 1;

  const int rt = blockIdx.x % (M1 / 128);
  const int ct = blockIdx.x / (M1 / 128);
  const int row0 = rt * 128, col0 = ct * 128;

  f32x4 acc[4][4] = {};

  const unsigned short* Ag = A + (size_t)row0 * K;
  const unsigned short* Bg = Bt + (size_t)col0 * K;

  auto stage = [&](int buf, int kt) {
    const unsigned short* ga = Ag + kt * 32;
    const unsigned short* gb = Bg + kt * 32;
#pragma unroll
    for (int j = 0; j < 2; j++) {
      int c = j * 256 + w * 64 + l;
      int r = c >> 2, s = c & 3;
      int ss = s ^ ((r >> 1) & 3);           // XOR swizzle (inverse applied on read)
      gll16(ga + (size_t)r * K + ss * 8, &As[buf][(j * 256 + w * 64) * 8]);
      gll16(gb + (size_t)r * K + ss * 8, &Bs[buf][(j * 256 + w * 64) * 8]);
    }
  };

  stage(0, 0);
  __syncthreads();

  int buf = 0;
  for (int kt = 0; kt < NK; kt++) {
    if (kt + 1 < NK) stage(buf ^ 1, kt + 1);

    bf16x8 af[4], bfr[4];
#pragma unroll
    for (int m = 0; m < 4; m++) {
      int r = wr * 64 + m * 16 + ln;
      int sl = kg ^ ((r >> 1) & 3);
      af[m] = lds_frag(&As[buf][r * 32 + sl * 8]);
    }
#pragma unroll
    for (int n = 0; n < 4; n++) {
      int r = wc * 64 + n * 16 + ln;
      int sl = kg ^ ((r >> 1) & 3);
      bfr[n] = lds_frag(&Bs[buf][r * 32 + sl * 8]);
    }
    __builtin_amdgcn_s_setprio(1);
#pragma unroll
    for (int m = 0; m < 4; m++)
#pragma unroll
      for (int n = 0; n < 4; n++)
        acc[m][n] = __builtin_amdgcn_mfma_f32_16x16x32_bf16(af[m], bfr[n], acc[m][n], 0, 0, 0);
    __builtin_amdgcn_s_setprio(0);

    __syncthreads();
    buf ^= 1;
  }

  // epilogue: C/D layout col = ln, row = kg*4 + reg (within 16x16)
  constexpr float QS = 0.18033688011112042f;   // log2(e)/8 : fold 1/sqrt(D)*log2e into Q
#pragma unroll
  for (int n = 0; n < 4; n++) {
    int col = col0 + wc * 64 + n * 16 + ln;
    float bv = bias[col];
    if constexpr (EPI == 1) {
      int three = col >> 10, rem = col & 1023;
      int h = rem >> 6, d = rem & 63;
#pragma unroll
      for (int m = 0; m < 4; m++)
#pragma unroll
        for (int r = 0; r < 4; r++) {
          int row = row0 + wr * 64 + m * 16 + kg * 4 + r;
          int bb = row >> 10, nn = row & 1023;
          float v = acc[m][n][r] + bv;
          size_t o = ((size_t)(bb * 16 + h) * 1024 + nn) * 64 + d;
          if (three == 0)      Qp[o] = f2bf(v * QS);
          else if (three == 1) Kp[o] = f2bf(v);
          else                 Vp[o] = f2bf(v);     // coalesced now; transposed later
        }
    } else {
#pragma unroll
      for (int m = 0; m < 4; m++)
#pragma unroll
        for (int r = 0; r < 4; r++) {
          int row = row0 + wr * 64 + m * 16 + kg * 4 + r;
          Out[(size_t)row * 1024 + col] = acc[m][n][r] + bv;
        }
    }
  }
}

// ---------------- flash attention, swapped-QK^T softmax ----------------
// grid (128 bh, 8 q-tiles) -> blocks sharing a head land on one XCD.
// 4 waves x 32 q-rows, KVBLK=64. S^T = mfma(K, Q): lane owns 16 key-scores of
// q=m*16+ln -> in-lane softmax + 2 shfl_xor. Defer-max (THR=8, log2 domain).
__global__ __launch_bounds__(256, 3)
void k_attn(const unsigned short* __restrict__ Qg, const unsigned short* __restrict__ Kg,
            const unsigned short* __restrict__ Vtg, unsigned short* __restrict__ AO) {
  __shared__ unsigned short Ks[2][64 * 64];
  __shared__ unsigned short Vs[2][64 * 64];
  __shared__ unsigned short Pl[4][32 * 72];   // [q][key], stride 72 elems (144B)

  const int tid = threadIdx.x;
  const int w = tid >> 6, l = tid & 63;
  const int ln = l & 15, kg = l >> 4;

  const int bh = blockIdx.x;
  const int qt = blockIdx.y;
  const int qbase = qt * 128 + w * 32;

  // Q fragments (pre-scaled by log2e/sqrt(D) in GEMM1 epilogue)
  bf16x8 qf[2][2];
#pragma unroll
  for (int m = 0; m < 2; m++)
#pragma unroll
    for (int kk = 0; kk < 2; kk++) {
      size_t off = ((size_t)bh * 1024 + qbase + m * 16 + ln) * 64 + kk * 32 + kg * 8;
      qf[m][kk] = __builtin_bit_cast(bf16x8, *(const u16x8*)(Qg + off));
    }

  f32x4 acc[2][4] = {};
  float mrun[2] = { -1e30f, -1e30f };
  float lrun[2] = { 0.f, 0.f };

  const unsigned short* Kbh = Kg + (size_t)bh * 1024 * 64;
  const unsigned short* Vbh = Vtg + (size_t)bh * 64 * 1024;

  auto stage = [&](int buf, int t) {
#pragma unroll
    for (int j = 0; j < 2; j++) {
      int c = j * 256 + w * 64 + l;
      int r = c >> 3, s = c & 7;
      int ss = s ^ (r & 7);
      gll16(Kbh + (size_t)(t * 64 + r) * 64 + ss * 8, &Ks[buf][(j * 256 + w * 64) * 8]);
      gll16(Vbh + (size_t)r * 1024 + t * 64 + ss * 8, &Vs[buf][(j * 256 + w * 64) * 8]);
    }
  };

  stage(0, 0);
  __syncthreads();

  int buf = 0;
  for (int t = 0; t < 16; t++) {
    if (t + 1 < 16) stage(buf ^ 1, t + 1);

    // S^T = K Q^T : s[m][n][r] = S[key = n*16+kg*4+r][q = qbase+m*16+ln]
    f32x4 s[2][4] = {};
    __builtin_amdgcn_s_setprio(1);
#pragma unroll
    for (int kk = 0; kk < 2; kk++) {
      bf16x8 kb[4];
#pragma unroll
      for (int n = 0; n < 4; n++) {
        int key = n * 16 + ln;
        int slot = (kk * 4 + kg) ^ (key & 7);
        kb[n] = lds_frag(&Ks[buf][key * 64 + slot * 8]);
      }
#pragma unroll
      for (int m = 0; m < 2; m++)
#pragma unroll
        for (int n = 0; n < 4; n++)
          s[m][n] = __builtin_amdgcn_mfma_f32_16x16x32_bf16(kb[n], qf[m][kk], s[m][n], 0, 0, 0);
    }
    __builtin_amdgcn_s_setprio(0);

    // ---- softmax (log2 domain), per lane: 16 scores for q = m*16+ln ----
    float p[2][4][4];
    float tmax[2];
#pragma unroll
    for (int m = 0; m < 2; m++) {
      float t0 = fmaxf(fmaxf(s[m][0][0], s[m][0][1]), fmaxf(s[m][0][2], s[m][0][3]));
      float t1 = fmaxf(fmaxf(s[m][1][0], s[m][1][1]), fmaxf(s[m][1][2], s[m][1][3]));
      float t2 = fmaxf(fmaxf(s[m][2][0], s[m][2][1]), fmaxf(s[m][2][2], s[m][2][3]));
      float t3 = fmaxf(fmaxf(s[m][3][0], s[m][3][1]), fmaxf(s[m][3][2], s[m][3][3]));
      float tm = fmaxf(fmaxf(t0, t1), fmaxf(t2, t3));
      tm = fmaxf(tm, __shfl_xor(tm, 16));
      tm = fmaxf(tm, __shfl_xor(tm, 32));
      tmax[m] = tm;
    }
    int cnd = (tmax[0] <= mrun[0] + 8.f) && (tmax[1] <= mrun[1] + 8.f);
    if (__all(cnd)) {
      // defer-max: keep old max, p bounded by 2^8
#pragma unroll
      for (int m = 0; m < 2; m++) {
        float rs = 0.f;
#pragma unroll
        for (int n = 0; n < 4; n++)
#pragma unroll
          for (int r = 0; r < 4; r++) {
            float pv = fexp2(s[m][n][r] - mrun[m]);
            p[m][n][r] = pv;
            rs += pv;
          }
        rs += __shfl_xor(rs, 16);
        rs += __shfl_xor(rs, 32);
        lrun[m] += rs;
      }
    } else {
      float al[2];
#pragma unroll
      for (int m = 0; m < 2; m++) {
        float mnew = fmaxf(mrun[m], tmax[m]);
        al[m] = fexp2(mrun[m] - mnew);
        mrun[m] = mnew;
        float rs = 0.f;
#pragma unroll
        for (int n = 0; n < 4; n++)
#pragma unroll
          for (int r = 0; r < 4; r++) {
            float pv = fexp2(s[m][n][r] - mnew);
            p[m][n][r] = pv;
            rs += pv;
          }
        rs += __shfl_xor(rs, 16);
        rs += __shfl_xor(rs, 32);
        lrun[m] = lrun[m] * al[m] + rs;
      }
#pragma unroll
      for (int m = 0; m < 2; m++)
#pragma unroll
        for (int r = 0; r < 4; r++) {
          float aq = __shfl(al[m], kg * 4 + r);   // alpha of q-row kg*4+r
#pragma unroll
          for (int n = 0; n < 4; n++) acc[m][n][r] *= aq;
        }
    }

    // ---- P -> LDS, packed b64 (keys kg*4..kg*4+3 contiguous) ----
#pragma unroll
    for (int m = 0; m < 2; m++)
#pragma unroll
      for (int n = 0; n < 4; n++) {
        u16x4 pk = { f2bf(p[m][n][0]), f2bf(p[m][n][1]), f2bf(p[m][n][2]), f2bf(p[m][n][3]) };
        *(u16x4*)&Pl[w][(m * 16 + ln) * 72 + n * 16 + kg * 4] = pk;
      }

    // ---- O += P V ----
    __builtin_amdgcn_s_setprio(1);
#pragma unroll
    for (int kk = 0; kk < 2; kk++) {
      bf16x8 pa[2];
#pragma unroll
      for (int m = 0; m < 2; m++)
        pa[m] = lds_frag(&Pl[w][(m * 16 + ln) * 72 + kk * 32 + kg * 8]);
#pragma unroll
      for (int n = 0; n < 4; n++) {
        int d = n * 16 + ln;
        int slot = (kk * 4 + kg) ^ (d & 7);
        bf16x8 vb = lds_frag(&Vs[buf][d * 64 + slot * 8]);
#pragma unroll
        for (int m = 0; m < 2; m++)
          acc[m][n] = __builtin_amdgcn_mfma_f32_16x16x32_bf16(pa[m], vb, acc[m][n], 0, 0, 0);
      }
    }
    __builtin_amdgcn_s_setprio(0);

    __syncthreads();
    buf ^= 1;
  }

  // normalize + store AO [B,N,H*D] bf16; acc row q = m*16+kg*4+r, lrun held at q=m*16+ln
  const int b = bh >> 4, h = bh & 15;
#pragma unroll
  for (int m = 0; m < 2; m++) {
    float linv = 1.f / lrun[m];
#pragma unroll
    for (int r = 0; r < 4; r++) {
      float lq = __shfl(linv, kg * 4 + r);
      int row = qbase + m * 16 + kg * 4 + r;
#pragma unroll
      for (int n = 0; n < 4; n++) {
        int col = h * 64 + n * 16 + ln;
        AO[((size_t)(b * 1024 + row)) * 1024 + col] = f2bf(acc[m][n][r] * lq);
      }
    }
  }
}

// ---------------- launch ----------------
extern "C" void kernel_launch(void* const* d_in, const int* in_sizes, int n_in,
                              void* d_out, int out_size, void* d_ws, size_t ws_size,
                              hipStream_t stream) {
  const float* x      = (const float*)d_in[0];
  const float* w_qkv  = (const float*)d_in[1];
  const float* b_qkv  = (const float*)d_in[2];
  const float* w_proj = (const float*)d_in[3];
  const float* b_proj = (const float*)d_in[4];
  float* out = (float*)d_out;

  constexpr size_t SZ_XB  = (size_t)8192 * 1024 * 2;         // 16.78 MB
  constexpr size_t SZ_WQ  = (size_t)3072 * 1024 * 2;         //  6.29 MB
  constexpr size_t SZ_WP  = (size_t)1024 * 1024 * 2;         //  2.10 MB
  constexpr size_t SZ_QKV = (size_t)8 * 16 * 1024 * 64 * 2;  // 16.78 MB each
  char* ws = (char*)d_ws;
  unsigned short* xb     = (unsigned short*)(ws);
  unsigned short* wqkvT  = (unsigned short*)(ws + SZ_XB);
  unsigned short* wprojT = (unsigned short*)(ws + SZ_XB + SZ_WQ);
  unsigned short* Qb     = (unsigned short*)(ws + SZ_XB + SZ_WQ + SZ_WP);
  unsigned short* Kb     = (unsigned short*)(ws + SZ_XB + SZ_WQ + SZ_WP + SZ_QKV);
  unsigned short* Vtb    = (unsigned short*)(ws + SZ_XB + SZ_WQ + SZ_WP + 2 * SZ_QKV);
  unsigned short* VrawAO = (unsigned short*)(ws + SZ_XB + SZ_WQ + SZ_WP + 3 * SZ_QKV);
  size_t needed = SZ_XB + SZ_WQ + SZ_WP + 4 * SZ_QKV;        // ~92.3 MB
  if (ws_size < needed) return;

  k_cvt<<<8192, 256, 0, stream>>>(x, xb, 8192 * 1024 / 4);
  dim3 tb(32, 8);
  k_tr_cvt<<<dim3(96, 32), tb, 0, stream>>>(w_qkv, wqkvT, 1024, 3072);
  k_tr_cvt<<<dim3(32, 32), tb, 0, stream>>>(w_proj, wprojT, 1024, 1024);
  // QKV GEMM -> Q(scaled), K, Vraw (all [B,H,N,D], coalesced stores)
  k_gemm<1, 3072><<<64 * 24, 256, 0, stream>>>(xb, wqkvT, b_qkv, Qb, Kb, VrawAO, nullptr);
  // transpose V -> Vt [B,H,D,N]
  k_tr_v<<<dim3(2, 32, 128), tb, 0, stream>>>(VrawAO, Vtb);
  // flash attention -> AO (aliases Vraw; Vraw dead after k_tr_v)
  k_attn<<<dim3(128, 8), 256, 0, stream>>>(Qb, Kb, Vtb, VrawAO);
  // projection -> out fp32
  k_gemm<2, 1024><<<64 * 8, 256, 0, stream>>>(VrawAO, wprojT, b_proj, nullptr, nullptr, nullptr, out);
}

// Round 5
// 246.223 us; speedup vs baseline: 1.3076x; 1.2506x over previous
//
#include <hip/hip_runtime.h>
#include <stdint.h>
#include <stddef.h>

// Multi-head attention: x@w_qkv+b -> heads -> softmax(QK^T/sqrt(D))V -> @w_proj+b
// B=8 N=1024 C=1024 H=16 D=64. bf16 MFMA, fp32 accum, fp32 softmax (log2 domain).
// Attention uses 32x32x16 swapped-operand MFMA + in-register P redistribution
// via v_cvt_pk_bf16_f32 + v_permlane32_swap_b32 (no P LDS buffer).

#define DEVI __device__ __forceinline__

typedef float f32x4 __attribute__((ext_vector_type(4)));
typedef float f32x16 __attribute__((ext_vector_type(16)));
typedef __bf16 bf16x8 __attribute__((ext_vector_type(8)));
typedef unsigned short u16x8 __attribute__((ext_vector_type(8)));
typedef unsigned short u16x4 __attribute__((ext_vector_type(4)));
typedef unsigned int u32;
typedef unsigned int u32x4 __attribute__((ext_vector_type(4)));

static constexpr int M1 = 8192;   // B*N rows

DEVI unsigned short f2bf(float f) {
  uint32_t u = __builtin_bit_cast(uint32_t, f);
  u += 0x7FFFu + ((u >> 16) & 1u);   // RNE
  return (unsigned short)(u >> 16);
}

DEVI float fexp2(float x) {
  float r;
  asm("v_exp_f32 %0, %1" : "=v"(r) : "v"(x));
  return r;
}

DEVI u32 cvtpk(float lo, float hi) {   // dst.lo16=bf16(lo), dst.hi16=bf16(hi)
  u32 r;
  asm("v_cvt_pk_bf16_f32 %0, %1, %2" : "=v"(r) : "v"(lo), "v"(hi));
  return r;
}

DEVI void plswap(u32& a, u32& b) {     // a.hi32lanes <-> b.lo32lanes
  asm("v_permlane32_swap_b32 %0, %1" : "+v"(a), "+v"(b));
}

DEVI void gll16(const unsigned short* g, unsigned short* lds) {
  __builtin_amdgcn_global_load_lds(
      (const __attribute__((address_space(1))) void*)g,
      (__attribute__((address_space(3))) void*)lds, 16, 0, 0);
}

DEVI bf16x8 lds_frag(const unsigned short* p) {
  return __builtin_bit_cast(bf16x8, *(const u16x8*)p);
}

// ---------------- convert x fp32 -> bf16 ----------------
__global__ void k_cvt(const float* __restrict__ in, unsigned short* __restrict__ out, int n4) {
  int i = blockIdx.x * blockDim.x + threadIdx.x;
  if (i < n4) {
    float4 v = reinterpret_cast<const float4*>(in)[i];
    u16x4 o = { f2bf(v.x), f2bf(v.y), f2bf(v.z), f2bf(v.w) };
    reinterpret_cast<u16x4*>(out)[i] = o;
  }
}

// ---------------- transpose + convert weights: in[R][C] fp32 -> out[C][R] bf16 ----------------
__global__ void k_tr_cvt(const float* __restrict__ in, unsigned short* __restrict__ out,
                         int R, int Cc) {
  __shared__ float tile[32][33];
  int c0 = blockIdx.x * 32, r0 = blockIdx.y * 32;
  int tx = threadIdx.x, ty = threadIdx.y;   // blockDim (32,8)
#pragma unroll
  for (int j = 0; j < 32; j += 8)
    tile[ty + j][tx] = in[(size_t)(r0 + ty + j) * Cc + c0 + tx];
  __syncthreads();
#pragma unroll
  for (int j = 0; j < 32; j += 8)
    out[(size_t)(c0 + ty + j) * R + r0 + tx] = f2bf(tile[tx][ty + j]);
}

// ---------------- bf16 transpose V[bh][n][64] -> Vt[bh][64][n] ----------------
__global__ void k_tr_v(const unsigned short* __restrict__ in, unsigned short* __restrict__ out) {
  __shared__ unsigned short t[32][33];
  int d0 = blockIdx.x * 32, n0 = blockIdx.y * 32, bh = blockIdx.z;
  const unsigned short* ip = in + (size_t)bh * 1024 * 64;
  unsigned short* op = out + (size_t)bh * 64 * 1024;
  int tx = threadIdx.x, ty = threadIdx.y;   // blockDim (32,8)
#pragma unroll
  for (int j = 0; j < 32; j += 8)
    t[ty + j][tx] = ip[(size_t)(n0 + ty + j) * 64 + d0 + tx];
  __syncthreads();
#pragma unroll
  for (int j = 0; j < 32; j += 8)
    op[(size_t)(d0 + ty + j) * 1024 + n0 + tx] = t[tx][ty + j];
}

// ---------------- GEMM: C[M x NCOLS] = A[M x 1024] * Bt[NCOLS x 1024]^T ----------------
template <int EPI, int NCOLS>
__global__ __launch_bounds__(256, 2)
void k_gemm(const unsigned short* __restrict__ A,
            const unsigned short* __restrict__ Bt,
            const float* __restrict__ bias,
            unsigned short* __restrict__ Qp,
            unsigned short* __restrict__ Kp,
            unsigned short* __restrict__ Vp,
            float* __restrict__ Out) {
  constexpr int K = 1024, NK = K / 32;
  __shared__ unsigned short As[2][128 * 32];
  __shared__ unsigned short Bs[2][128 * 32];

  const int tid = threadIdx.x;
  const int w = tid >> 6, l = tid & 63;
  const int ln = l & 15, kg = l >> 4;
  const int wr = w >> 1, wc = w & 1;

  const int rt = blockIdx.x % (M1 / 128);
  const int ct = blockIdx.x / (M1 / 128);
  const int row0 = rt * 128, col0 = ct * 128;

  f32x4 acc[4][4] = {};

  const unsigned short* Ag = A + (size_t)row0 * K;
  const unsigned short* Bg = Bt + (size_t)col0 * K;

  auto stage = [&](int buf, int kt) {
    const unsigned short* ga = Ag + kt * 32;
    const unsigned short* gb = Bg + kt * 32;
#pragma unroll
    for (int j = 0; j < 2; j++) {
      int c = j * 256 + w * 64 + l;
      int r = c >> 2, s = c & 3;
      int ss = s ^ ((r >> 1) & 3);
      gll16(ga + (size_t)r * K + ss * 8, &As[buf][(j * 256 + w * 64) * 8]);
      gll16(gb + (size_t)r * K + ss * 8, &Bs[buf][(j * 256 + w * 64) * 8]);
    }
  };

  stage(0, 0);
  __syncthreads();

  int buf = 0;
  for (int kt = 0; kt < NK; kt++) {
    if (kt + 1 < NK) stage(buf ^ 1, kt + 1);

    bf16x8 af[4], bfr[4];
#pragma unroll
    for (int m = 0; m < 4; m++) {
      int r = wr * 64 + m * 16 + ln;
      int sl = kg ^ ((r >> 1) & 3);
      af[m] = lds_frag(&As[buf][r * 32 + sl * 8]);
    }
#pragma unroll
    for (int n = 0; n < 4; n++) {
      int r = wc * 64 + n * 16 + ln;
      int sl = kg ^ ((r >> 1) & 3);
      bfr[n] = lds_frag(&Bs[buf][r * 32 + sl * 8]);
    }
    __builtin_amdgcn_s_setprio(1);
#pragma unroll
    for (int m = 0; m < 4; m++)
#pragma unroll
      for (int n = 0; n < 4; n++)
        acc[m][n] = __builtin_amdgcn_mfma_f32_16x16x32_bf16(af[m], bfr[n], acc[m][n], 0, 0, 0);
    __builtin_amdgcn_s_setprio(0);

    __syncthreads();
    buf ^= 1;
  }

  // epilogue, n-innermost so 128B lines are filled by consecutive stores (WC-friendly)
  constexpr float QS = 0.18033688011112042f;   // log2(e)/8
  float bv[4];
#pragma unroll
  for (int n = 0; n < 4; n++) bv[n] = bias[col0 + wc * 64 + n * 16 + ln];

  if constexpr (EPI == 1) {
    const int three = col0 >> 10;               // which tensor (Q/K/V)
    const int h = ((col0 & 1023) >> 6) + wc;    // head (64 cols per wave = one head)
    unsigned short* tgt = (three == 0) ? Qp : (three == 1) ? Kp : Vp;
    const float sc = (three == 0) ? QS : 1.f;
#pragma unroll
    for (int m = 0; m < 4; m++)
#pragma unroll
      for (int r = 0; r < 4; r++) {
        int row = row0 + wr * 64 + m * 16 + kg * 4 + r;
        int bb = row >> 10, nn = row & 1023;
        size_t base = ((size_t)(bb * 16 + h) * 1024 + nn) * 64;
#pragma unroll
        for (int n = 0; n < 4; n++)
          tgt[base + n * 16 + ln] = f2bf((acc[m][n][r] + bv[n]) * sc);
      }
  } else {
#pragma unroll
    for (int m = 0; m < 4; m++)
#pragma unroll
      for (int r = 0; r < 4; r++) {
        int row = row0 + wr * 64 + m * 16 + kg * 4 + r;
#pragma unroll
        for (int n = 0; n < 4; n++)
          Out[(size_t)row * 1024 + col0 + wc * 64 + n * 16 + ln] = acc[m][n][r] + bv[n];
      }
  }
}

// ---------------- flash attention, 32x32x16 swapped MFMA ----------------
// grid (128 bh, 8 q-tiles); 4 waves x 32 q-rows, KVBLK=64.
// S^T = mfma(K,Q): lane owns q=l&31, keys (r&3)+8*(r>>2)+4*(l>>5) per 32-key block.
// P redistribution to A-operand: cvt_pk pairs + permlane32_swap (l <-> l^32 only).
__global__ __launch_bounds__(256, 4)
void k_attn(const unsigned short* __restrict__ Qg, const unsigned short* __restrict__ Kg,
            const unsigned short* __restrict__ Vtg, unsigned short* __restrict__ AO) {
  __shared__ unsigned short Ks[2][64 * 64];
  __shared__ unsigned short Vs[2][64 * 64];

  const int tid = threadIdx.x;
  const int w = tid >> 6, l = tid & 63;
  const int lq = l & 31, b = l >> 5;

  const int bh = blockIdx.x;
  const int qt = blockIdx.y;
  const int qbase = qt * 128 + w * 32;

  // Q as B-operand: lane holds Q[qbase+lq][kk*16 + b*8 + j]  (pre-scaled log2e/8)
  bf16x8 qf[4];
#pragma unroll
  for (int kk = 0; kk < 4; kk++) {
    size_t off = ((size_t)bh * 1024 + qbase + lq) * 64 + kk * 16 + b * 8;
    qf[kk] = __builtin_bit_cast(bf16x8, *(const u16x8*)(Qg + off));
  }

  f32x16 acc[2] = {};                 // O[q=(r&3)+8(r>>2)+4b][d=n*32+lq]
  float mrun = -1e30f, lrun = 0.f;    // for q = lq (lanes l, l^32 duplicate)

  const unsigned short* Kbh = Kg + (size_t)bh * 1024 * 64;
  const unsigned short* Vbh = Vtg + (size_t)bh * 64 * 1024;

  auto stage = [&](int buf, int t) {
#pragma unroll
    for (int j = 0; j < 2; j++) {
      int c = j * 256 + w * 64 + l;
      int r = c >> 3, s = c & 7;
      int ss = s ^ (r & 7);
      gll16(Kbh + (size_t)(t * 64 + r) * 64 + ss * 8, &Ks[buf][(j * 256 + w * 64) * 8]);
      gll16(Vbh + (size_t)r * 1024 + t * 64 + ss * 8, &Vs[buf][(j * 256 + w * 64) * 8]);
    }
  };

  stage(0, 0);
  __syncthreads();

  int buf = 0;
  for (int t = 0; t < 16; t++) {
    if (t + 1 < 16) stage(buf ^ 1, t + 1);

    // ---- S^T = K Q^T : s[kb] covers keys kb*32.. ----
    f32x16 s[2];
    __builtin_amdgcn_s_setprio(1);
#pragma unroll
    for (int kb = 0; kb < 2; kb++) {
      f32x16 z = {};
#pragma unroll
      for (int kk = 0; kk < 4; kk++) {
        int row = kb * 32 + lq;
        int ss = (kk * 2 + b) ^ (row & 7);
        bf16x8 kf = lds_frag(&Ks[buf][row * 64 + ss * 8]);
        z = __builtin_amdgcn_mfma_f32_32x32x16_bf16(kf, qf[kk], z, 0, 0, 0);
      }
      s[kb] = z;
    }
    __builtin_amdgcn_s_setprio(0);

    // ---- softmax (log2 domain), lane-local q = lq ----
    float tm = s[0][0];
#pragma unroll
    for (int kb = 0; kb < 2; kb++)
#pragma unroll
      for (int r = 0; r < 16; r++) tm = fmaxf(tm, s[kb][r]);
    tm = fmaxf(tm, __shfl_xor(tm, 32));

    if (!__all(tm <= mrun + 8.f)) {
      float mnew = fmaxf(mrun, tm);
      float al = fexp2(mrun - mnew);
      mrun = mnew;
      lrun *= al;
#pragma unroll
      for (int r = 0; r < 16; r++) {
        float aq = __shfl(al, (r & 3) + 8 * (r >> 2) + 4 * b);
        acc[0][r] *= aq;
        acc[1][r] *= aq;
      }
    }

    float rs = 0.f;
#pragma unroll
    for (int kb = 0; kb < 2; kb++)
#pragma unroll
      for (int r = 0; r < 16; r++) {
        float pv = fexp2(s[kb][r] - mrun);
        s[kb][r] = pv;
        rs += pv;
      }
    rs += __shfl_xor(rs, 32);
    lrun += rs;

    // ---- P -> A-operand frags: pa[step], step covers keys step*16.. ----
    bf16x8 pa[4];
#pragma unroll
    for (int kb = 0; kb < 2; kb++) {
      u32 pk[4][2];
#pragma unroll
      for (int t4 = 0; t4 < 4; t4++) {
        pk[t4][0] = cvtpk(s[kb][t4 * 4 + 0], s[kb][t4 * 4 + 1]);
        pk[t4][1] = cvtpk(s[kb][t4 * 4 + 2], s[kb][t4 * 4 + 3]);
      }
#pragma unroll
      for (int sh = 0; sh < 2; sh++) {
        u32 a0 = pk[2 * sh][0], b0 = pk[2 * sh + 1][0];
        plswap(a0, b0);
        u32 a1 = pk[2 * sh][1], b1 = pk[2 * sh + 1][1];
        plswap(a1, b1);
        u32x4 fr = { a0, a1, b0, b1 };
        pa[kb * 2 + sh] = __builtin_bit_cast(bf16x8, fr);
      }
    }

    // ---- O += P V ----
    __builtin_amdgcn_s_setprio(1);
#pragma unroll
    for (int n = 0; n < 2; n++) {
#pragma unroll
      for (int st = 0; st < 4; st++) {
        int row = n * 32 + lq;
        int ss = (st * 2 + b) ^ (row & 7);
        bf16x8 vb = lds_frag(&Vs[buf][row * 64 + ss * 8]);
        acc[n] = __builtin_amdgcn_mfma_f32_32x32x16_bf16(pa[st], vb, acc[n], 0, 0, 0);
      }
    }
    __builtin_amdgcn_s_setprio(0);

    __syncthreads();
    buf ^= 1;
  }

  // ---- normalize + store AO [B,N,H*D] bf16 ----
  const int bb = bh >> 4, h = bh & 15;
  float linv = 1.f / lrun;
#pragma unroll
  for (int r = 0; r < 16; r++) {
    float lq_r = __shfl(linv, (r & 3) + 8 * (r >> 2) + 4 * b);
    int row = qbase + (r & 3) + 8 * (r >> 2) + 4 * b;
    size_t base = ((size_t)(bb * 1024 + row)) * 1024 + h * 64;
#pragma unroll
    for (int n = 0; n < 2; n++)
      AO[base + n * 32 + lq] = f2bf(acc[n][r] * lq_r);
  }
}

// ---------------- launch ----------------
extern "C" void kernel_launch(void* const* d_in, const int* in_sizes, int n_in,
                              void* d_out, int out_size, void* d_ws, size_t ws_size,
                              hipStream_t stream) {
  const float* x      = (const float*)d_in[0];
  const float* w_qkv  = (const float*)d_in[1];
  const float* b_qkv  = (const float*)d_in[2];
  const float* w_proj = (const float*)d_in[3];
  const float* b_proj = (const float*)d_in[4];
  float* out = (float*)d_out;

  constexpr size_t SZ_XB  = (size_t)8192 * 1024 * 2;
  constexpr size_t SZ_WQ  = (size_t)3072 * 1024 * 2;
  constexpr size_t SZ_WP  = (size_t)1024 * 1024 * 2;
  constexpr size_t SZ_QKV = (size_t)8 * 16 * 1024 * 64 * 2;
  char* ws = (char*)d_ws;
  unsigned short* xb     = (unsigned short*)(ws);
  unsigned short* wqkvT  = (unsigned short*)(ws + SZ_XB);
  unsigned short* wprojT = (unsigned short*)(ws + SZ_XB + SZ_WQ);
  unsigned short* Qb     = (unsigned short*)(ws + SZ_XB + SZ_WQ + SZ_WP);
  unsigned short* Kb     = (unsigned short*)(ws + SZ_XB + SZ_WQ + SZ_WP + SZ_QKV);
  unsigned short* Vtb    = (unsigned short*)(ws + SZ_XB + SZ_WQ + SZ_WP + 2 * SZ_QKV);
  unsigned short* VrawAO = (unsigned short*)(ws + SZ_XB + SZ_WQ + SZ_WP + 3 * SZ_QKV);
  size_t needed = SZ_XB + SZ_WQ + SZ_WP + 4 * SZ_QKV;
  if (ws_size < needed) return;

  k_cvt<<<8192, 256, 0, stream>>>(x, xb, 8192 * 1024 / 4);
  dim3 tb(32, 8);
  k_tr_cvt<<<dim3(96, 32), tb, 0, stream>>>(w_qkv, wqkvT, 1024, 3072);
  k_tr_cvt<<<dim3(32, 32), tb, 0, stream>>>(w_proj, wprojT, 1024, 1024);
  k_gemm<1, 3072><<<64 * 24, 256, 0, stream>>>(xb, wqkvT, b_qkv, Qb, Kb, VrawAO, nullptr);
  k_tr_v<<<dim3(2, 32, 128), tb, 0, stream>>>(VrawAO, Vtb);
  k_attn<<<dim3(128, 8), 256, 0, stream>>>(Qb, Kb, Vtb, VrawAO);
  k_gemm<2, 1024><<<64 * 8, 256, 0, stream>>>(VrawAO, wprojT, b_proj, nullptr, nullptr, nullptr, out);
}